// Round 7
// baseline (597.741 us; speedup 1.0000x reference)
//
#include <hip/hip_runtime.h>

#define NN     50000
#define NE     200000
#define ETOT   250000   // NE + NN self-loops
#define FIN    165
#define KP1    192      // FIN padded to 3*64 K-tiles
#define HEADS  8
#define CH     100
#define DIM    800      // 8*100
#define MPAD   50176    // 196*256
#define NP1    1024     // 4*256  (pad of 816: 800 data + 16 es/ed)
#define DIM2   1600     // W2|Wres1 fused output
#define KP2    832      // 800 padded to 13*64 K-tiles
#define NP2    1792     // 7*256  (pad of 1616: 1600 data + 16 es/ed)
#define NEG    0.2f

typedef unsigned short u16;
typedef unsigned int   u32;
typedef __bf16 bf16x8 __attribute__((ext_vector_type(8)));
typedef float  f32x4  __attribute__((ext_vector_type(4)));

__device__ __forceinline__ u16 f2b(float f) {
  u32 u = __float_as_uint(f);
  u = (u + 0x7FFFu + ((u >> 16) & 1u)) >> 16;   // RNE
  return (u16)u;
}
__device__ __forceinline__ float b2f(u16 u) { return __uint_as_float(((u32)u) << 16); }

// ---------------- CSR build (dst -> list of src), reused by all 3 layers ----------------
__global__ void k_count(const int* __restrict__ ei, int* __restrict__ cnt) {
  int e = blockIdx.x * 256 + threadIdx.x;
  if (e >= ETOT) return;
  int d = (e < NE) ? ei[NE + e] : (e - NE);
  atomicAdd(&cnt[d], 1);
}
__global__ void k_bsum(const int* __restrict__ cnt, int* __restrict__ bs) {
  __shared__ int sm[256];
  int i = blockIdx.x * 256 + threadIdx.x;
  sm[threadIdx.x] = (i < NN) ? cnt[i] : 0;
  __syncthreads();
  for (int off = 128; off; off >>= 1) {
    if (threadIdx.x < off) sm[threadIdx.x] += sm[threadIdx.x + off];
    __syncthreads();
  }
  if (!threadIdx.x) bs[blockIdx.x] = sm[0];
}
__global__ void k_top(int* __restrict__ bs, int* __restrict__ rs, int nb) {
  __shared__ int sm[256];
  int t = threadIdx.x;
  int v = (t < nb) ? bs[t] : 0;
  sm[t] = v; __syncthreads();
  for (int off = 1; off < 256; off <<= 1) {
    int add = (t >= off) ? sm[t - off] : 0;
    __syncthreads();
    sm[t] += add;
    __syncthreads();
  }
  if (t < nb) bs[t] = sm[t] - v;   // exclusive block offsets
  if (!t) rs[NN] = ETOT;
}
__global__ void k_scan(const int* __restrict__ cnt, const int* __restrict__ bs, int* __restrict__ rs) {
  __shared__ int sm[256];
  int t = threadIdx.x, i = blockIdx.x * 256 + t;
  int v = (i < NN) ? cnt[i] : 0;
  sm[t] = v; __syncthreads();
  for (int off = 1; off < 256; off <<= 1) {
    int add = (t >= off) ? sm[t - off] : 0;
    __syncthreads();
    sm[t] += add;
    __syncthreads();
  }
  if (i < NN) rs[i] = bs[blockIdx.x] + sm[t] - v;
}
__global__ void k_fill(const int* __restrict__ ei, const int* __restrict__ rs,
                       int* __restrict__ cur, int* __restrict__ esrc) {
  int e = blockIdx.x * 256 + threadIdx.x;
  if (e >= ETOT) return;
  int s, d;
  if (e < NE) { s = ei[e]; d = ei[NE + e]; } else { s = d = e - NE; }
  int pos = atomicAdd(&cur[d], 1);
  esrc[rs[d] + pos] = s;
}

// ---------------- converts (fp32 -> bf16, pad, transpose weights) ----------------
__global__ void k_cvt_x(const float* __restrict__ x, u16* __restrict__ A) {
  int idx = blockIdx.x * 256 + threadIdx.x;   // MPAD*KP1 exact
  int r = idx / KP1, k = idx - r * KP1;
  float v = (r < NN && k < FIN) ? x[r * FIN + k] : 0.f;
  A[idx] = f2b(v);
}
__global__ void k_cvt_w1(const float* __restrict__ W1, u16* __restrict__ Bt) {
  int idx = blockIdx.x * 256 + threadIdx.x;   // DIM*KP1 exact
  if (idx >= DIM * KP1) return;
  int j = idx / KP1, k = idx - j * KP1;
  float v = (k < FIN) ? W1[k * DIM + j] : 0.f;
  Bt[idx] = f2b(v);
}
__global__ void k_cvt_w2(const float* __restrict__ W2, const float* __restrict__ Wr1,
                         u16* __restrict__ Bt) {
  int idx = blockIdx.x * 256 + threadIdx.x;   // DIM2*KP2 exact
  if (idx >= DIM2 * KP2) return;
  int j = idx / KP2, k = idx - j * KP2;
  float v = 0.f;
  if (k < DIM) v = (j < DIM) ? W2[k * DIM + j] : Wr1[k * DIM + (j - DIM)];
  Bt[idx] = f2b(v);
}
// fused attention columns: Wt row (Dsp+j), j=h -> (W @ a_src blockdiag), j=8+h -> a_dst.
// es = (x@W)@a == x@(W@a) by associativity; rides along in the main GEMM for free.
__global__ void k_wa(const float* __restrict__ W, const float* __restrict__ as,
                     const float* __restrict__ ad, u16* __restrict__ Wt,
                     int Kin, int Kpad, int Dsp) {
  int idx = blockIdx.x * 256 + threadIdx.x;
  if (idx >= 16 * Kpad) return;
  int j = idx / Kpad, k = idx - j * Kpad;
  int h = j & 7;
  const float* a = ((j < 8) ? as : ad) + h * CH;
  float s = 0.f;
  if (k < Kin) {
    const float* wr = W + (size_t)k * DIM + h * CH;
    for (int c = 0; c < CH; ++c) s += wr[c] * a[c];
  }
  Wt[(size_t)(Dsp + j) * Kpad + k] = f2b(s);
}

// ------------- 256x256 MFMA GEMM, BK=64, 8 waves, T1+T2+T3/T4+T5 -------------
// LDS: A/B 256x64 bf16 tiles (32KB each), double-buffered = 128KB.
// T2 layout per 128-row half: subtile = (row>>4)*2 + (col>>5); inner u16 =
//   (row&15)*32 + ((col&31) ^ (((row>>3)&1)<<4)).  gload_lds dest stays linear;
//   the GLOBAL source applies the inverse permutation; the ds_read applies the
//   same XOR, so delivered fragments are the UNpermuted k-blocks (MFMA-correct).
// Schedule per K-tile t: compute(buf[t&1]) ; barrier ; issue(t+2 into buf[t&1]) ;
//   vmcnt(8) (tile t+1 landed; never 0 mid-loop) ; barrier.
// Stores guarded by row < Mreal so C/es/ed buffers can be sized NN rows.
__device__ __forceinline__ void gl_lds16(const u16* g, u16* l) {
  __builtin_amdgcn_global_load_lds((const __attribute__((address_space(1))) void*)g,
                                   (__attribute__((address_space(3))) void*)l, 16, 0, 0);
}
#define WAITVM(N) asm volatile("s_waitcnt vmcnt(" #N ")" ::: "memory")

__global__ __launch_bounds__(512, 2) void k_gemm256(
    const u16* __restrict__ A, const u16* __restrict__ Bt, u16* __restrict__ C,
    float* __restrict__ es, float* __restrict__ ed,
    int Kpad, int NT, int Dsplit, int Nreal, int ldC, int Mreal) {
  __shared__ __align__(16) u16 lA[2][16384];
  __shared__ __align__(16) u16 lB[2][16384];
  const int t = threadIdx.x;
  const int lane = t & 63, w = t >> 6;
  const int wm = w >> 2, wn = w & 3;

  // T1 XCD swizzle (bijective chunked, m204)
  int nwg = gridDim.x * gridDim.y;
  int hid = blockIdx.y * gridDim.x + blockIdx.x;
  int q = nwg >> 3, r8 = nwg & 7;
  int xcd = hid & 7, i8 = hid >> 3;
  int ln = (xcd < r8 ? xcd * (q + 1) : r8 * (q + 1) + (xcd - r8) * q) + i8;
  int tn = (ln % gridDim.x) * 256, tm = (ln / gridDim.x) * 256;

  // staging source address = inverse of the subtiled+XOR LDS layout
  const int srow = ((w >> 1) << 4) + (lane >> 2);                       // 0..63
  const int scol = ((w & 1) << 5) + (((lane & 3) * 8) ^ (((lane >> 5) & 1) << 4));
  const size_t rA = (size_t)(tm + srow) * Kpad + scol;
  const size_t rB = (size_t)(tn + srow) * Kpad + scol;
  const size_t oR = (size_t)64 * Kpad;
  const int dul = w * 512 + lane * 8;   // LDS dest u16 offset, linear

  f32x4 acc[8][4];
#pragma unroll
  for (int i = 0; i < 8; ++i)
#pragma unroll
    for (int j = 0; j < 4; ++j) acc[i][j] = (f32x4){0.f, 0.f, 0.f, 0.f};

  auto issue = [&](int buf, int kt) {
    const u16* pa = A + rA + (size_t)kt * 64;
    gl_lds16(pa,          &lA[buf][dul]);
    gl_lds16(pa + oR,     &lA[buf][4096 + dul]);
    gl_lds16(pa + 2 * oR, &lA[buf][8192 + dul]);
    gl_lds16(pa + 3 * oR, &lA[buf][12288 + dul]);
    const u16* pb = Bt + rB + (size_t)kt * 64;
    gl_lds16(pb,          &lB[buf][dul]);
    gl_lds16(pb + oR,     &lB[buf][4096 + dul]);
    gl_lds16(pb + 2 * oR, &lB[buf][8192 + dul]);
    gl_lds16(pb + 3 * oR, &lB[buf][12288 + dul]);
  };

  const int rl = lane & 15, kl = (lane >> 4) * 8;
  const int rdoff = rl * 32 + (kl ^ (((rl >> 3) & 1) << 4));

  issue(0, 0);
  if (NT > 1) issue(1, 1);
  WAITVM(8);                       // tile 0 landed (tile 1's 8 may still fly)
  __builtin_amdgcn_s_barrier();

  for (int kt = 0; kt < NT; ++kt) {
    const int buf = kt & 1;
    const u16* baseA = &lA[buf][wm * 8192];
    const u16* baseB = &lB[buf][(wn >> 1) * 8192];
    bf16x8 b[4][2];
#pragma unroll
    for (int fc = 0; fc < 4; ++fc)
#pragma unroll
      for (int kk = 0; kk < 2; ++kk)
        b[fc][kk] = *(const bf16x8*)&baseB[((((wn & 1) * 4 + fc) * 2 + kk) << 9) + rdoff];
#pragma unroll
    for (int qm = 0; qm < 2; ++qm) {
      bf16x8 a[4][2];
#pragma unroll
      for (int i = 0; i < 4; ++i)
#pragma unroll
        for (int kk = 0; kk < 2; ++kk)
          a[i][kk] = *(const bf16x8*)&baseA[((((qm * 4 + i) * 2) + kk) << 9) + rdoff];
      __builtin_amdgcn_s_setprio(1);
#pragma unroll
      for (int i = 0; i < 4; ++i)
#pragma unroll
        for (int fc = 0; fc < 4; ++fc)
#pragma unroll
          for (int kk = 0; kk < 2; ++kk)
            acc[qm * 4 + i][fc] =
                __builtin_amdgcn_mfma_f32_16x16x32_bf16(a[i][kk], b[fc][kk], acc[qm * 4 + i][fc], 0, 0, 0);
      __builtin_amdgcn_s_setprio(0);
    }
    __builtin_amdgcn_s_barrier();          // all waves done reading buf
    if (kt + 2 < NT) { issue(buf, kt + 2); WAITVM(8); }
    else             { WAITVM(0); }
    __builtin_amdgcn_s_barrier();          // next tile visible to all waves
    __builtin_amdgcn_sched_barrier(0);
  }

  const int rq = (lane >> 4) * 4;
#pragma unroll
  for (int fr = 0; fr < 8; ++fr) {
#pragma unroll
    for (int fc = 0; fc < 4; ++fc) {
      int col = tn + wn * 64 + fc * 16 + rl;
      if (col < Dsplit) {
#pragma unroll
        for (int q2 = 0; q2 < 4; ++q2) {
          int row = tm + wm * 128 + fr * 16 + rq + q2;
          if (row < Mreal) C[(size_t)row * ldC + col] = f2b(acc[fr][fc][q2]);
        }
      } else if (col < Nreal) {
        int cj = col - Dsplit;
        float* dst = (cj < 8) ? es : ed;
        int hh = cj & 7;
#pragma unroll
        for (int q2 = 0; q2 < 4; ++q2) {
          int row = tm + wm * 128 + fr * 16 + rq + q2;
          if (row < Mreal) dst[(size_t)row * 8 + hh] = acc[fr][fc][q2];
        }
      }
    }
  }
}

// ---- per-(node,head) softmax stats; single pass (shift-invariant, m=0), stores exp ----
__global__ void k_stats(const int* __restrict__ rs, const int* __restrict__ esrc,
                        const float* __restrict__ es, const float* __restrict__ ed,
                        float* __restrict__ ex, float* __restrict__ dv) {
  int idx = blockIdx.x * 256 + threadIdx.x;
  if (idx >= NN * HEADS) return;
  int n = idx >> 3, h = idx & 7;
  int beg = rs[n], end = rs[n + 1];
  float edv = ed[idx];
  float den = 0.f;
  for (int j = beg; j < end; ++j) {
    float x = es[esrc[j] * 8 + h] + edv;
    x = x > 0.f ? x : NEG * x;
    float e = __expf(x);
    ex[j * 8 + h] = e;
    den += e;
  }
  dv[idx] = 1.f / (den + 1e-16f);
}

// ---- aggregation: hot loop is ex-broadcast + ushort4 gather + FMA only ----
// LAYER 1: in = H1p (stride DIM), out = GEMM2 A-matrix (stride KP2; cols/rows
//          beyond [NN]x[800) are never meaningfully consumed — B's matching
//          k-rows are zero, C pad rows unstored).
// LAYER 2: in = G2 (stride DIM2), resid = G2 cols [800,1600), out stride DIM.
template <int LAYER>
__global__ __launch_bounds__(256) void k_agg(const int* __restrict__ rs, const int* __restrict__ esrc,
    const u16* __restrict__ Hp, const float* __restrict__ ex, const float* __restrict__ dv,
    const float* __restrict__ bias, const u16* __restrict__ resid, u16* __restrict__ out) {
  const int ld  = (LAYER == 2) ? DIM2 : DIM;
  const int old = (LAYER == 1) ? KP2 : DIM;
  int n = blockIdx.x, t = threadIdx.x;
  if (t >= 200) return;
  int beg = rs[n], end = rs[n + 1];
  int c = t * 4;
  int h = t / 25;
  float inv = dv[n * 8 + h];
  float a0 = 0.f, a1 = 0.f, a2 = 0.f, a3 = 0.f;
  for (int j = beg; j < end; ++j) {
    int s = esrc[j];
    float wv = ex[j * 8 + h];
    ushort4 u = *(const ushort4*)(Hp + (size_t)s * ld + c);
    a0 += wv * b2f(u.x); a1 += wv * b2f(u.y); a2 += wv * b2f(u.z); a3 += wv * b2f(u.w);
  }
  const float4 bb = *(const float4*)(bias + c);
  float v0 = a0 * inv + bb.x, v1 = a1 * inv + bb.y, v2 = a2 * inv + bb.z, v3 = a3 * inv + bb.w;
  if (LAYER == 2) {
    ushort4 r = *(const ushort4*)(resid + (size_t)n * DIM2 + c);
    v0 += b2f(r.x); v1 += b2f(r.y); v2 += b2f(r.z); v3 += b2f(r.w);
  }
  v0 = v0 > 0.f ? v0 : __expf(v0) - 1.f;
  v1 = v1 > 0.f ? v1 : __expf(v1) - 1.f;
  v2 = v2 > 0.f ? v2 : __expf(v2) - 1.f;
  v3 = v3 > 0.f ? v3 : __expf(v3) - 1.f;
  ushort4 o;
  o.x = f2b(v0); o.y = f2b(v1); o.z = f2b(v2); o.w = f2b(v3);
  *(ushort4*)(out + (size_t)n * old + c) = o;
}

// ---------------- layer 3: skinny projections, one wave per node ----------------
__global__ __launch_bounds__(256) void k_l3(const u16* __restrict__ h2, const float* __restrict__ x,
    const float* __restrict__ W3, const float* __restrict__ Wres2, const float* __restrict__ Wskip,
    const float* __restrict__ a3s, const float* __restrict__ a3d, const float* __restrict__ b3,
    float* __restrict__ H3p, float* __restrict__ base, float* __restrict__ es3, float* __restrict__ ed3) {
  int wv = threadIdx.x >> 6, lane = threadIdx.x & 63;
  int n = blockIdx.x * 4 + wv;
  if (n >= NN) return;
  float p0 = 0.f, p1 = 0.f, r0 = 0.f, r1 = 0.f;
  const u16* hr = h2 + (size_t)n * DIM;
  for (int c = lane; c < DIM; c += 64) {
    float v = b2f(hr[c]);
    p0 += v * W3[2 * c];    p1 += v * W3[2 * c + 1];
    r0 += v * Wres2[2 * c]; r1 += v * Wres2[2 * c + 1];
  }
  float s0 = 0.f, s1 = 0.f;
  const float* xr = x + (size_t)n * FIN;
  for (int c = lane; c < FIN; c += 64) {
    float v = xr[c];
    s0 += v * Wskip[2 * c]; s1 += v * Wskip[2 * c + 1];
  }
#pragma unroll
  for (int off = 32; off; off >>= 1) {
    p0 += __shfl_down(p0, off); p1 += __shfl_down(p1, off);
    r0 += __shfl_down(r0, off); r1 += __shfl_down(r1, off);
    s0 += __shfl_down(s0, off); s1 += __shfl_down(s1, off);
  }
  if (!lane) {
    H3p[2 * n] = p0; H3p[2 * n + 1] = p1;
    es3[n] = p0 * a3s[0] + p1 * a3s[1];
    ed3[n] = p0 * a3d[0] + p1 * a3d[1];
    base[2 * n]     = r0 + s0 + b3[0];
    base[2 * n + 1] = r1 + s1 + b3[1];
  }
}

// ---------------- layer 3 softmax+aggregate (1 head, 2 ch) -> final logits ----------------
__global__ void k_l3agg(const int* __restrict__ rs, const int* __restrict__ esrc,
                        const float* __restrict__ H3p, const float* __restrict__ base,
                        const float* __restrict__ es3, const float* __restrict__ ed3,
                        float* __restrict__ out) {
  int n = blockIdx.x * 256 + threadIdx.x;
  if (n >= NN) return;
  int beg = rs[n], end = rs[n + 1];
  float edv = ed3[n];
  float den = 0.f, a0 = 0.f, a1 = 0.f;
  for (int j = beg; j < end; ++j) {
    int s = esrc[j];
    float e = es3[s] + edv;
    e = e > 0.f ? e : NEG * e;
    float exv = __expf(e);
    den += exv;
    a0 += exv * H3p[2 * s];
    a1 += exv * H3p[2 * s + 1];
  }
  float inv = 1.f / (den + 1e-16f);
  out[2 * n]     = base[2 * n]     + a0 * inv;
  out[2 * n + 1] = base[2 * n + 1] + a1 * inv;
}

extern "C" void kernel_launch(void* const* d_in, const int* in_sizes, int n_in,
                              void* d_out, int out_size, void* d_ws, size_t ws_size,
                              hipStream_t stream) {
  (void)in_sizes; (void)n_in; (void)out_size; (void)ws_size;
  const float* x    = (const float*)d_in[0];
  const int*   ei   = (const int*)d_in[1];
  const float* W1   = (const float*)d_in[2];
  const float* a1s  = (const float*)d_in[3];
  const float* a1d  = (const float*)d_in[4];
  const float* b1   = (const float*)d_in[5];
  const float* W2   = (const float*)d_in[6];
  const float* a2s  = (const float*)d_in[7];
  const float* a2d  = (const float*)d_in[8];
  const float* b2   = (const float*)d_in[9];
  const float* W3   = (const float*)d_in[10];
  const float* a3s  = (const float*)d_in[11];
  const float* a3d  = (const float*)d_in[12];
  const float* b3   = (const float*)d_in[13];
  const float* Wr1  = (const float*)d_in[14];
  const float* Wr2  = (const float*)d_in[15];
  const float* Wsk  = (const float*)d_in[16];
  float* out = (float*)d_out;

  // ---- workspace layout (total ~260.9 MB; R6's 269.8 MB presumably overflowed 256 MiB) ----
  char* w = (char*)d_ws;
  size_t off = 0;
  auto alloc = [&](size_t bytes) { void* p = w + off; off += (bytes + 255) & ~(size_t)255; return p; };
  int* cnt   = (int*)alloc((size_t)NN * 4);
  int* cur   = (int*)alloc((size_t)NN * 4);
  int* rs    = (int*)alloc((size_t)(NN + 1) * 4);
  int* bs    = (int*)alloc(256 * 4);
  int* esrc  = (int*)alloc((size_t)ETOT * 4);
  float* es  = (float*)alloc((size_t)NN * HEADS * 4);
  float* ed  = (float*)alloc((size_t)NN * HEADS * 4);
  float* exb = (float*)alloc((size_t)ETOT * HEADS * 4);
  float* dvf = (float*)alloc((size_t)NN * HEADS * 4);
  u16* W2t   = (u16*)alloc((size_t)NP2 * KP2 * 2);
  u16* bufB  = (u16*)alloc((size_t)MPAD * KP2 * 2);    // GEMM2 A (stride KP2), later h2bf (stride DIM)
  u16* bufA  = (u16*)alloc((size_t)NN * DIM2 * 2);     // H1p | A1 | W1t zones, later G2
  // aliases inside bufA (zones dead when their successors are written):
  u16* H1p   = bufA;                                    // [0, NN*800)
  u16* A1    = bufA + (size_t)NN * DIM;                 // [NN*800, +MPAD*192)
  u16* W1t   = A1 + (size_t)MPAD * KP1;                 // [+, +1024*192) — dead before G2
  u16* G2    = bufA;                                    // GEMM2 C, stride 1600, rows < NN
  // aliases inside exb (exb dead after k_agg<2>; these written by k_l3 after):
  float* H3p  = exb;
  float* base = exb + 2 * NN;
  float* es3  = exb + 4 * NN;
  float* ed3  = exb + 5 * NN;

  const int nb = (NN + 255) / 256;        // 196
  const int ge = (ETOT + 255) / 256;      // 977
  const int gh = (NN * HEADS + 255) / 256;// 1563

  // CSR build
  hipMemsetAsync(cnt, 0, (size_t)NN * 4, stream);
  hipMemsetAsync(cur, 0, (size_t)NN * 4, stream);
  k_count<<<ge, 256, 0, stream>>>(ei, cnt);
  k_bsum <<<nb, 256, 0, stream>>>(cnt, bs);
  k_top  <<<1, 256, 0, stream>>>(bs, rs, nb);
  k_scan <<<nb, 256, 0, stream>>>(cnt, bs, rs);
  k_fill <<<ge, 256, 0, stream>>>(ei, rs, cur, esrc);

  // converts (+ fused es/ed weight columns)
  k_cvt_x <<<(MPAD * KP1) / 256, 256, 0, stream>>>(x, A1);
  k_cvt_w1<<<(DIM * KP1) / 256, 256, 0, stream>>>(W1, W1t);
  k_wa    <<<(16 * KP1) / 256, 256, 0, stream>>>(W1, a1s, a1d, W1t, FIN, KP1, DIM);
  k_cvt_w2<<<(DIM2 * KP2) / 256, 256, 0, stream>>>(W2, Wr1, W2t);
  k_wa    <<<(16 * KP2) / 256, 256, 0, stream>>>(W2, a2s, a2d, W2t, DIM, KP2, DIM2);

  // layer 1 (GEMM also emits es/ed via fused columns 800-815)
  k_gemm256<<<dim3(NP1 / 256, MPAD / 256), 512, 0, stream>>>(
      A1, W1t, H1p, es, ed, KP1, KP1 / 64, DIM, DIM + 16, DIM, NN);
  k_stats<<<gh, 256, 0, stream>>>(rs, esrc, es, ed, exb, dvf);
  k_agg<1><<<NN, 256, 0, stream>>>(rs, esrc, H1p, exb, dvf, b1, (const u16*)nullptr, bufB);

  // layer 2 (W2|Wres1 fused GEMM; es/ed via fused columns 1600-1615)
  k_gemm256<<<dim3(NP2 / 256, MPAD / 256), 512, 0, stream>>>(
      bufB, W2t, G2, es, ed, KP2, KP2 / 64, DIM2, DIM2 + 16, DIM2, NN);
  k_stats<<<gh, 256, 0, stream>>>(rs, esrc, es, ed, exb, dvf);
  k_agg<2><<<NN, 256, 0, stream>>>(rs, esrc, G2, exb, dvf, b2, G2 + DIM, bufB);

  // layer 3
  k_l3   <<<(NN + 3) / 4, 256, 0, stream>>>(bufB, x, W3, Wr2, Wsk, a3s, a3d, b3, H3p, base, es3, ed3);
  k_l3agg<<<nb, 256, 0, stream>>>(rs, esrc, H3p, base, es3, ed3, out);
}

// Round 8
// 587.032 us; speedup vs baseline: 1.0182x; 1.0182x over previous
//
#include <hip/hip_runtime.h>

#define NN     50000
#define NE     200000
#define ETOT   250000   // NE + NN self-loops
#define FIN    165
#define KP1    192      // FIN padded to 3*64 K-tiles
#define HEADS  8
#define CH     100
#define DIM    800      // 8*100
#define MPAD   50176    // 196*256
#define NP1    1024     // 4*256  (pad of 816: 800 data + 16 es/ed)
#define DIM2   1600     // W2|Wres1 fused output
#define KP2    832      // 800 padded to 13*64 K-tiles
#define NP2    1792     // 7*256  (pad of 1616: 1600 data + 16 es/ed)
#define NEG    0.2f

typedef unsigned short u16;
typedef unsigned int   u32;
typedef __bf16 bf16x8 __attribute__((ext_vector_type(8)));
typedef float  f32x4  __attribute__((ext_vector_type(4)));

__device__ __forceinline__ u16 f2b(float f) {
  u32 u = __float_as_uint(f);
  u = (u + 0x7FFFu + ((u >> 16) & 1u)) >> 16;   // RNE
  return (u16)u;
}
__device__ __forceinline__ float b2f(u16 u) { return __uint_as_float(((u32)u) << 16); }

// ---------------- CSR build (dst -> list of src), reused by all 3 layers ----------------
__global__ void k_count(const int* __restrict__ ei, int* __restrict__ cnt) {
  int e = blockIdx.x * 256 + threadIdx.x;
  if (e >= ETOT) return;
  int d = (e < NE) ? ei[NE + e] : (e - NE);
  atomicAdd(&cnt[d], 1);
}
__global__ void k_bsum(const int* __restrict__ cnt, int* __restrict__ bs) {
  __shared__ int sm[256];
  int i = blockIdx.x * 256 + threadIdx.x;
  sm[threadIdx.x] = (i < NN) ? cnt[i] : 0;
  __syncthreads();
  for (int off = 128; off; off >>= 1) {
    if (threadIdx.x < off) sm[threadIdx.x] += sm[threadIdx.x + off];
    __syncthreads();
  }
  if (!threadIdx.x) bs[blockIdx.x] = sm[0];
}
__global__ void k_top(int* __restrict__ bs, int* __restrict__ rs, int nb) {
  __shared__ int sm[256];
  int t = threadIdx.x;
  int v = (t < nb) ? bs[t] : 0;
  sm[t] = v; __syncthreads();
  for (int off = 1; off < 256; off <<= 1) {
    int add = (t >= off) ? sm[t - off] : 0;
    __syncthreads();
    sm[t] += add;
    __syncthreads();
  }
  if (t < nb) bs[t] = sm[t] - v;   // exclusive block offsets
  if (!t) rs[NN] = ETOT;
}
__global__ void k_scan(const int* __restrict__ cnt, const int* __restrict__ bs, int* __restrict__ rs) {
  __shared__ int sm[256];
  int t = threadIdx.x, i = blockIdx.x * 256 + t;
  int v = (i < NN) ? cnt[i] : 0;
  sm[t] = v; __syncthreads();
  for (int off = 1; off < 256; off <<= 1) {
    int add = (t >= off) ? sm[t - off] : 0;
    __syncthreads();
    sm[t] += add;
    __syncthreads();
  }
  if (i < NN) rs[i] = bs[blockIdx.x] + sm[t] - v;
}
__global__ void k_fill(const int* __restrict__ ei, const int* __restrict__ rs,
                       int* __restrict__ cur, int* __restrict__ esrc) {
  int e = blockIdx.x * 256 + threadIdx.x;
  if (e >= ETOT) return;
  int s, d;
  if (e < NE) { s = ei[e]; d = ei[NE + e]; } else { s = d = e - NE; }
  int pos = atomicAdd(&cur[d], 1);
  esrc[rs[d] + pos] = s;
}

// ---------------- converts (fp32 -> bf16, pad, transpose weights) ----------------
__global__ void k_cvt_x(const float* __restrict__ x, u16* __restrict__ A) {
  int idx = blockIdx.x * 256 + threadIdx.x;   // MPAD*KP1 exact
  int r = idx / KP1, k = idx - r * KP1;
  float v = (r < NN && k < FIN) ? x[r * FIN + k] : 0.f;
  A[idx] = f2b(v);
}
__global__ void k_cvt_w1(const float* __restrict__ W1, u16* __restrict__ Bt) {
  int idx = blockIdx.x * 256 + threadIdx.x;   // DIM*KP1 exact
  if (idx >= DIM * KP1) return;
  int j = idx / KP1, k = idx - j * KP1;
  float v = (k < FIN) ? W1[k * DIM + j] : 0.f;
  Bt[idx] = f2b(v);
}
__global__ void k_cvt_w2(const float* __restrict__ W2, const float* __restrict__ Wr1,
                         u16* __restrict__ Bt) {
  int idx = blockIdx.x * 256 + threadIdx.x;   // DIM2*KP2 exact
  if (idx >= DIM2 * KP2) return;
  int j = idx / KP2, k = idx - j * KP2;
  float v = 0.f;
  if (k < DIM) v = (j < DIM) ? W2[k * DIM + j] : Wr1[k * DIM + (j - DIM)];
  Bt[idx] = f2b(v);
}
// fused attention columns: Wt row (Dsp+j), j=h -> (W @ a_src blockdiag), j=8+h -> a_dst.
__global__ void k_wa(const float* __restrict__ W, const float* __restrict__ as,
                     const float* __restrict__ ad, u16* __restrict__ Wt,
                     int Kin, int Kpad, int Dsp) {
  int idx = blockIdx.x * 256 + threadIdx.x;
  if (idx >= 16 * Kpad) return;
  int j = idx / Kpad, k = idx - j * Kpad;
  int h = j & 7;
  const float* a = ((j < 8) ? as : ad) + h * CH;
  float s = 0.f;
  if (k < Kin) {
    const float* wr = W + (size_t)k * DIM + h * CH;
    for (int c = 0; c < CH; ++c) s += wr[c] * a[c];
  }
  Wt[(size_t)(Dsp + j) * Kpad + k] = f2b(s);
}

// ------------- 256x256 MFMA GEMM, BK=64, 8 waves, T1+T2+T3/T4+T5 -------------
// R7 layout/addressing kept bit-identical (T2 both-sides swizzle -> 0 bank conflicts).
// NEW: fine 4-phase interleave per K-tile (m201/m196: the per-phase interleave is
// the lever; coarse split is null). Phase p: {ds_read subtile ; issue 2 staging
// ops for tile kt+1 into buf[1-p] ; barrier ; 16 MFMA (setprio) ; [vmcnt] barrier}.
// Issue order A0,A2 | B0,B1 | B2,B3 | A1,A3 matches consumption order so waits
// are COUNTED: vmcnt(4) at phase-1 end publishes current tile's A1/A3;
// vmcnt(2) at phase-3 end publishes next tile's first 6 ops. Never 0 mid-loop.
// WAR-safe: issues into buf[1-p] start only after the barrier that ended the
// iteration which read buf[1-p]. All barriers are asm with memory clobber so
// the compiler cannot hoist LDS reads across publication points.
__device__ __forceinline__ void gl_lds16(const u16* g, u16* l) {
  __builtin_amdgcn_global_load_lds((const __attribute__((address_space(1))) void*)g,
                                   (__attribute__((address_space(3))) void*)l, 16, 0, 0);
}
#define WAITVM(N) asm volatile("s_waitcnt vmcnt(" #N ")" ::: "memory")
#define BARRIER() asm volatile("s_barrier" ::: "memory")

__global__ __launch_bounds__(512, 2) void k_gemm256(
    const u16* __restrict__ A, const u16* __restrict__ Bt, u16* __restrict__ C,
    float* __restrict__ es, float* __restrict__ ed,
    int Kpad, int NT, int Dsplit, int Nreal, int ldC, int Mreal) {
  __shared__ __align__(16) u16 lA[2][16384];
  __shared__ __align__(16) u16 lB[2][16384];
  const int t = threadIdx.x;
  const int lane = t & 63, w = t >> 6;
  const int wm = w >> 2, wn = w & 3;

  // T1 XCD swizzle (bijective chunked, m204)
  int nwg = gridDim.x * gridDim.y;
  int hid = blockIdx.y * gridDim.x + blockIdx.x;
  int q = nwg >> 3, r8 = nwg & 7;
  int xcd = hid & 7, i8 = hid >> 3;
  int ln = (xcd < r8 ? xcd * (q + 1) : r8 * (q + 1) + (xcd - r8) * q) + i8;
  int tn = (ln % gridDim.x) * 256, tm = (ln / gridDim.x) * 256;

  // staging source address = inverse of the subtiled+XOR LDS layout (R7-proven)
  const int srow = ((w >> 1) << 4) + (lane >> 2);                       // 0..63
  const int scol = ((w & 1) << 5) + (((lane & 3) * 8) ^ (((lane >> 5) & 1) << 4));
  const size_t rA = (size_t)(tm + srow) * Kpad + scol;
  const size_t rB = (size_t)(tn + srow) * Kpad + scol;
  const size_t oR = (size_t)64 * Kpad;
  const int dul = w * 512 + lane * 8;   // LDS dest u16 offset, linear

  f32x4 acc[8][4];
#pragma unroll
  for (int i = 0; i < 8; ++i)
#pragma unroll
    for (int j = 0; j < 4; ++j) acc[i][j] = (f32x4){0.f, 0.f, 0.f, 0.f};

  auto issueA1 = [&](int buf, int kt, int op) {
    gl_lds16(A + rA + (size_t)kt * 64 + (size_t)op * oR, &lA[buf][op * 4096 + dul]);
  };
  auto issueB1 = [&](int buf, int kt, int op) {
    gl_lds16(Bt + rB + (size_t)kt * 64 + (size_t)op * oR, &lB[buf][op * 4096 + dul]);
  };

  const int rl = lane & 15, kl = (lane >> 4) * 8;
  const int rdoff = rl * 32 + (kl ^ (((rl >> 3) & 1) << 4));

  // prologue: tile 0, full drain (simple)
  issueA1(0, 0, 0); issueA1(0, 0, 1); issueA1(0, 0, 2); issueA1(0, 0, 3);
  issueB1(0, 0, 0); issueB1(0, 0, 1); issueB1(0, 0, 2); issueB1(0, 0, 3);
  WAITVM(0);
  BARRIER();

  for (int kt = 0; kt < NT; ++kt) {
    const int p = kt & 1, nb2 = p ^ 1, kn = kt + 1;
    const bool pf = (kn < NT);
    const u16* baseA = &lA[p][wm * 8192];
    const u16* baseB = &lB[p][(wn >> 1) * 8192];
    bf16x8 b[4][2];
    bf16x8 af[2][2];

    // ---- phase 0: read all B (8) + A fr0-1 (4); issue A0,A2(next) ----
#pragma unroll
    for (int fc = 0; fc < 4; ++fc)
#pragma unroll
      for (int kk = 0; kk < 2; ++kk)
        b[fc][kk] = *(const bf16x8*)&baseB[((((wn & 1) * 4 + fc) * 2 + kk) << 9) + rdoff];
#pragma unroll
    for (int j = 0; j < 2; ++j)
#pragma unroll
      for (int kk = 0; kk < 2; ++kk)
        af[j][kk] = *(const bf16x8*)&baseA[((j * 2 + kk) << 9) + rdoff];
    if (pf) { issueA1(nb2, kn, 0); issueA1(nb2, kn, 2); }
    BARRIER();
    __builtin_amdgcn_s_setprio(1);
#pragma unroll
    for (int j = 0; j < 2; ++j)
#pragma unroll
      for (int fc = 0; fc < 4; ++fc)
#pragma unroll
        for (int kk = 0; kk < 2; ++kk)
          acc[j][fc] = __builtin_amdgcn_mfma_f32_16x16x32_bf16(af[j][kk], b[fc][kk], acc[j][fc], 0, 0, 0);
    __builtin_amdgcn_s_setprio(0);
    BARRIER();

    // ---- phase 1: read A fr2-3; issue B0,B1(next); publish A1/A3 of CURRENT ----
#pragma unroll
    for (int j = 0; j < 2; ++j)
#pragma unroll
      for (int kk = 0; kk < 2; ++kk)
        af[j][kk] = *(const bf16x8*)&baseA[(((2 + j) * 2 + kk) << 9) + rdoff];
    if (pf) { issueB1(nb2, kn, 0); issueB1(nb2, kn, 1); }
    BARRIER();
    __builtin_amdgcn_s_setprio(1);
#pragma unroll
    for (int j = 0; j < 2; ++j)
#pragma unroll
      for (int fc = 0; fc < 4; ++fc)
#pragma unroll
        for (int kk = 0; kk < 2; ++kk)
          acc[2 + j][fc] = __builtin_amdgcn_mfma_f32_16x16x32_bf16(af[j][kk], b[fc][kk], acc[2 + j][fc], 0, 0, 0);
    __builtin_amdgcn_s_setprio(0);
    if (pf) { WAITVM(4); } else { WAITVM(0); }
    BARRIER();

    // ---- phase 2: read A fr4-5; issue B2,B3(next) ----
#pragma unroll
    for (int j = 0; j < 2; ++j)
#pragma unroll
      for (int kk = 0; kk < 2; ++kk)
        af[j][kk] = *(const bf16x8*)&baseA[(((4 + j) * 2 + kk) << 9) + rdoff];
    if (pf) { issueB1(nb2, kn, 2); issueB1(nb2, kn, 3); }
    BARRIER();
    __builtin_amdgcn_s_setprio(1);
#pragma unroll
    for (int j = 0; j < 2; ++j)
#pragma unroll
      for (int fc = 0; fc < 4; ++fc)
#pragma unroll
        for (int kk = 0; kk < 2; ++kk)
          acc[4 + j][fc] = __builtin_amdgcn_mfma_f32_16x16x32_bf16(af[j][kk], b[fc][kk], acc[4 + j][fc], 0, 0, 0);
    __builtin_amdgcn_s_setprio(0);
    BARRIER();

    // ---- phase 3: read A fr6-7; issue A1,A3(next); publish next tile's first 6 ----
#pragma unroll
    for (int j = 0; j < 2; ++j)
#pragma unroll
      for (int kk = 0; kk < 2; ++kk)
        af[j][kk] = *(const bf16x8*)&baseA[(((6 + j) * 2 + kk) << 9) + rdoff];
    if (pf) { issueA1(nb2, kn, 1); issueA1(nb2, kn, 3); }
    BARRIER();
    __builtin_amdgcn_s_setprio(1);
#pragma unroll
    for (int j = 0; j < 2; ++j)
#pragma unroll
      for (int fc = 0; fc < 4; ++fc)
#pragma unroll
        for (int kk = 0; kk < 2; ++kk)
          acc[6 + j][fc] = __builtin_amdgcn_mfma_f32_16x16x32_bf16(af[j][kk], b[fc][kk], acc[6 + j][fc], 0, 0, 0);
    __builtin_amdgcn_s_setprio(0);
    WAITVM(2);
    BARRIER();
  }

  const int rq = (lane >> 4) * 4;
#pragma unroll
  for (int fr = 0; fr < 8; ++fr) {
#pragma unroll
    for (int fc = 0; fc < 4; ++fc) {
      int col = tn + wn * 64 + fc * 16 + rl;
      if (col < Dsplit) {
#pragma unroll
        for (int q2 = 0; q2 < 4; ++q2) {
          int row = tm + wm * 128 + fr * 16 + rq + q2;
          if (row < Mreal) C[(size_t)row * ldC + col] = f2b(acc[fr][fc][q2]);
        }
      } else if (col < Nreal) {
        int cj = col - Dsplit;
        float* dst = (cj < 8) ? es : ed;
        int hh = cj & 7;
#pragma unroll
        for (int q2 = 0; q2 < 4; ++q2) {
          int row = tm + wm * 128 + fr * 16 + rq + q2;
          if (row < Mreal) dst[(size_t)row * 8 + hh] = acc[fr][fc][q2];
        }
      }
    }
  }
}

// ---- per-(node,head) softmax stats; single pass (shift-invariant, m=0), stores exp ----
__global__ void k_stats(const int* __restrict__ rs, const int* __restrict__ esrc,
                        const float* __restrict__ es, const float* __restrict__ ed,
                        float* __restrict__ ex, float* __restrict__ dv) {
  int idx = blockIdx.x * 256 + threadIdx.x;
  if (idx >= NN * HEADS) return;
  int n = idx >> 3, h = idx & 7;
  int beg = rs[n], end = rs[n + 1];
  float edv = ed[idx];
  float den = 0.f;
  for (int j = beg; j < end; ++j) {
    float x = es[esrc[j] * 8 + h] + edv;
    x = x > 0.f ? x : NEG * x;
    float e = __expf(x);
    ex[j * 8 + h] = e;
    den += e;
  }
  dv[idx] = 1.f / (den + 1e-16f);
}

// ---- aggregation: hot loop is ex-broadcast + ushort4 gather + FMA only ----
template <int LAYER>
__global__ __launch_bounds__(256) void k_agg(const int* __restrict__ rs, const int* __restrict__ esrc,
    const u16* __restrict__ Hp, const float* __restrict__ ex, const float* __restrict__ dv,
    const float* __restrict__ bias, const u16* __restrict__ resid, u16* __restrict__ out) {
  const int ld  = (LAYER == 2) ? DIM2 : DIM;
  const int old = (LAYER == 1) ? KP2 : DIM;
  int n = blockIdx.x, t = threadIdx.x;
  if (t >= 200) return;
  int beg = rs[n], end = rs[n + 1];
  int c = t * 4;
  int h = t / 25;
  float inv = dv[n * 8 + h];
  float a0 = 0.f, a1 = 0.f, a2 = 0.f, a3 = 0.f;
  for (int j = beg; j < end; ++j) {
    int s = esrc[j];
    float wv = ex[j * 8 + h];
    ushort4 u = *(const ushort4*)(Hp + (size_t)s * ld + c);
    a0 += wv * b2f(u.x); a1 += wv * b2f(u.y); a2 += wv * b2f(u.z); a3 += wv * b2f(u.w);
  }
  const float4 bb = *(const float4*)(bias + c);
  float v0 = a0 * inv + bb.x, v1 = a1 * inv + bb.y, v2 = a2 * inv + bb.z, v3 = a3 * inv + bb.w;
  if (LAYER == 2) {
    ushort4 r = *(const ushort4*)(resid + (size_t)n * DIM2 + c);
    v0 += b2f(r.x); v1 += b2f(r.y); v2 += b2f(r.z); v3 += b2f(r.w);
  }
  v0 = v0 > 0.f ? v0 : __expf(v0) - 1.f;
  v1 = v1 > 0.f ? v1 : __expf(v1) - 1.f;
  v2 = v2 > 0.f ? v2 : __expf(v2) - 1.f;
  v3 = v3 > 0.f ? v3 : __expf(v3) - 1.f;
  ushort4 o;
  o.x = f2b(v0); o.y = f2b(v1); o.z = f2b(v2); o.w = f2b(v3);
  *(ushort4*)(out + (size_t)n * old + c) = o;
}

// ---------------- layer 3: skinny projections, one wave per node ----------------
__global__ __launch_bounds__(256) void k_l3(const u16* __restrict__ h2, const float* __restrict__ x,
    const float* __restrict__ W3, const float* __restrict__ Wres2, const float* __restrict__ Wskip,
    const float* __restrict__ a3s, const float* __restrict__ a3d, const float* __restrict__ b3,
    float* __restrict__ H3p, float* __restrict__ base, float* __restrict__ es3, float* __restrict__ ed3) {
  int wv = threadIdx.x >> 6, lane = threadIdx.x & 63;
  int n = blockIdx.x * 4 + wv;
  if (n >= NN) return;
  float p0 = 0.f, p1 = 0.f, r0 = 0.f, r1 = 0.f;
  const u16* hr = h2 + (size_t)n * DIM;
  for (int c = lane; c < DIM; c += 64) {
    float v = b2f(hr[c]);
    p0 += v * W3[2 * c];    p1 += v * W3[2 * c + 1];
    r0 += v * Wres2[2 * c]; r1 += v * Wres2[2 * c + 1];
  }
  float s0 = 0.f, s1 = 0.f;
  const float* xr = x + (size_t)n * FIN;
  for (int c = lane; c < FIN; c += 64) {
    float v = xr[c];
    s0 += v * Wskip[2 * c]; s1 += v * Wskip[2 * c + 1];
  }
#pragma unroll
  for (int off = 32; off; off >>= 1) {
    p0 += __shfl_down(p0, off); p1 += __shfl_down(p1, off);
    r0 += __shfl_down(r0, off); r1 += __shfl_down(r1, off);
    s0 += __shfl_down(s0, off); s1 += __shfl_down(s1, off);
  }
  if (!lane) {
    H3p[2 * n] = p0; H3p[2 * n + 1] = p1;
    es3[n] = p0 * a3s[0] + p1 * a3s[1];
    ed3[n] = p0 * a3d[0] + p1 * a3d[1];
    base[2 * n]     = r0 + s0 + b3[0];
    base[2 * n + 1] = r1 + s1 + b3[1];
  }
}

// ---------------- layer 3 softmax+aggregate (1 head, 2 ch) -> final logits ----------------
__global__ void k_l3agg(const int* __restrict__ rs, const int* __restrict__ esrc,
                        const float* __restrict__ H3p, const float* __restrict__ base,
                        const float* __restrict__ es3, const float* __restrict__ ed3,
                        float* __restrict__ out) {
  int n = blockIdx.x * 256 + threadIdx.x;
  if (n >= NN) return;
  int beg = rs[n], end = rs[n + 1];
  float edv = ed3[n];
  float den = 0.f, a0 = 0.f, a1 = 0.f;
  for (int j = beg; j < end; ++j) {
    int s = esrc[j];
    float e = es3[s] + edv;
    e = e > 0.f ? e : NEG * e;
    float exv = __expf(e);
    den += exv;
    a0 += exv * H3p[2 * s];
    a1 += exv * H3p[2 * s + 1];
  }
  float inv = 1.f / (den + 1e-16f);
  out[2 * n]     = base[2 * n]     + a0 * inv;
  out[2 * n + 1] = base[2 * n + 1] + a1 * inv;
}

extern "C" void kernel_launch(void* const* d_in, const int* in_sizes, int n_in,
                              void* d_out, int out_size, void* d_ws, size_t ws_size,
                              hipStream_t stream) {
  (void)in_sizes; (void)n_in; (void)out_size; (void)ws_size;
  const float* x    = (const float*)d_in[0];
  const int*   ei   = (const int*)d_in[1];
  const float* W1   = (const float*)d_in[2];
  const float* a1s  = (const float*)d_in[3];
  const float* a1d  = (const float*)d_in[4];
  const float* b1   = (const float*)d_in[5];
  const float* W2   = (const float*)d_in[6];
  const float* a2s  = (const float*)d_in[7];
  const float* a2d  = (const float*)d_in[8];
  const float* b2   = (const float*)d_in[9];
  const float* W3   = (const float*)d_in[10];
  const float* a3s  = (const float*)d_in[11];
  const float* a3d  = (const float*)d_in[12];
  const float* b3   = (const float*)d_in[13];
  const float* Wr1  = (const float*)d_in[14];
  const float* Wr2  = (const float*)d_in[15];
  const float* Wsk  = (const float*)d_in[16];
  float* out = (float*)d_out;

  // ---- workspace layout (~260.9 MB) ----
  char* w = (char*)d_ws;
  size_t off = 0;
  auto alloc = [&](size_t bytes) { void* p = w + off; off += (bytes + 255) & ~(size_t)255; return p; };
  int* cnt   = (int*)alloc((size_t)NN * 4);
  int* cur   = (int*)alloc((size_t)NN * 4);
  int* rs    = (int*)alloc((size_t)(NN + 1) * 4);
  int* bs    = (int*)alloc(256 * 4);
  int* esrc  = (int*)alloc((size_t)ETOT * 4);
  float* es  = (float*)alloc((size_t)NN * HEADS * 4);
  float* ed  = (float*)alloc((size_t)NN * HEADS * 4);
  float* exb = (float*)alloc((size_t)ETOT * HEADS * 4);
  float* dvf = (float*)alloc((size_t)NN * HEADS * 4);
  u16* W2t   = (u16*)alloc((size_t)NP2 * KP2 * 2);
  u16* bufB  = (u16*)alloc((size_t)MPAD * KP2 * 2);    // GEMM2 A (stride KP2), later h2bf (stride DIM)
  u16* bufA  = (u16*)alloc((size_t)NN * DIM2 * 2);     // H1p | A1 | W1t zones, later G2
  u16* H1p   = bufA;                                    // [0, NN*800)
  u16* A1    = bufA + (size_t)NN * DIM;                 // [NN*800, +MPAD*192)
  u16* W1t   = A1 + (size_t)MPAD * KP1;                 // dead before G2
  u16* G2    = bufA;                                    // GEMM2 C, stride 1600, rows < NN
  float* H3p  = exb;
  float* base = exb + 2 * NN;
  float* es3  = exb + 4 * NN;
  float* ed3  = exb + 5 * NN;

  const int nb = (NN + 255) / 256;        // 196
  const int ge = (ETOT + 255) / 256;      // 977
  const int gh = (NN * HEADS + 255) / 256;// 1563

  // CSR build
  hipMemsetAsync(cnt, 0, (size_t)NN * 4, stream);
  hipMemsetAsync(cur, 0, (size_t)NN * 4, stream);
  k_count<<<ge, 256, 0, stream>>>(ei, cnt);
  k_bsum <<<nb, 256, 0, stream>>>(cnt, bs);
  k_top  <<<1, 256, 0, stream>>>(bs, rs, nb);
  k_scan <<<nb, 256, 0, stream>>>(cnt, bs, rs);
  k_fill <<<ge, 256, 0, stream>>>(ei, rs, cur, esrc);

  // converts (+ fused es/ed weight columns)
  k_cvt_x <<<(MPAD * KP1) / 256, 256, 0, stream>>>(x, A1);
  k_cvt_w1<<<(DIM * KP1) / 256, 256, 0, stream>>>(W1, W1t);
  k_wa    <<<(16 * KP1) / 256, 256, 0, stream>>>(W1, a1s, a1d, W1t, FIN, KP1, DIM);
  k_cvt_w2<<<(DIM2 * KP2) / 256, 256, 0, stream>>>(W2, Wr1, W2t);
  k_wa    <<<(16 * KP2) / 256, 256, 0, stream>>>(W2, a2s, a2d, W2t, DIM, KP2, DIM2);

  // layer 1 (GEMM also emits es/ed via fused columns 800-815)
  k_gemm256<<<dim3(NP1 / 256, MPAD / 256), 512, 0, stream>>>(
      A1, W1t, H1p, es, ed, KP1, KP1 / 64, DIM, DIM + 16, DIM, NN);
  k_stats<<<gh, 256, 0, stream>>>(rs, esrc, es, ed, exb, dvf);
  k_agg<1><<<NN, 256, 0, stream>>>(rs, esrc, H1p, exb, dvf, b1, (const u16*)nullptr, bufB);

  // layer 2 (W2|Wres1 fused GEMM; es/ed via fused columns 1600-1615)
  k_gemm256<<<dim3(NP2 / 256, MPAD / 256), 512, 0, stream>>>(
      bufB, W2t, G2, es, ed, KP2, KP2 / 64, DIM2, DIM2 + 16, DIM2, NN);
  k_stats<<<gh, 256, 0, stream>>>(rs, esrc, es, ed, exb, dvf);
  k_agg<2><<<NN, 256, 0, stream>>>(rs, esrc, G2, exb, dvf, b2, G2 + DIM, bufB);

  // layer 3
  k_l3   <<<(NN + 3) / 4, 256, 0, stream>>>(bufB, x, W3, Wr2, Wsk, a3s, a3d, b3, H3p, base, es3, ed3);
  k_l3agg<<<nb, 256, 0, stream>>>(rs, esrc, H3p, base, es3, ed3, out);
}